// Round 9
// baseline (516.655 us; speedup 1.0000x reference)
//
#include <hip/hip_runtime.h>
#include <hip/hip_bf16.h>

#define DEV static __device__ __forceinline__

typedef float f32x4 __attribute__((ext_vector_type(4)));
typedef __bf16 b16x8 __attribute__((ext_vector_type(8)));

DEV unsigned short f2bf(float f) {
  union { __hip_bfloat16 h; unsigned short u; } cv;
  cv.h = __float2bfloat16(f);
  return cv.u;
}

DEV void gload_lds16(const unsigned short* g, unsigned short* l) {
  __builtin_amdgcn_global_load_lds(
      (__attribute__((address_space(1))) void*)g,
      (__attribute__((address_space(3))) void*)l, 16, 0, 0);
}

// ---------------- f32 -> bf16 elementwise ----------------
__global__ __launch_bounds__(256) void k_conv_bf16(const float* __restrict__ src,
                                                   unsigned short* __restrict__ dst,
                                                   long long n4) {
  long long i = (long long)blockIdx.x * 256 + threadIdx.x;
  if (i >= n4) return;
  const float4 v = ((const float4*)src)[i];
  ushort4 o;
  o.x = f2bf(v.x); o.y = f2bf(v.y); o.z = f2bf(v.z); o.w = f2bf(v.w);
  ((ushort4*)dst)[i] = o;
}

// ---------------- f32 [z][R][C] -> bf16 [z][C][R] ----------------
__global__ __launch_bounds__(256) void k_transpose_bf16(const float* __restrict__ src,
                                                        unsigned short* __restrict__ dst,
                                                        int R, int C) {
  __shared__ float t[32][33];
  const long long zo = (long long)blockIdx.z * R * C;
  const int c0 = blockIdx.x * 32, r0 = blockIdx.y * 32;
  const int tx = threadIdx.x, ty = threadIdx.y;
#pragma unroll
  for (int i = 0; i < 4; ++i)
    t[ty + i * 8][tx] = src[zo + (long long)(r0 + ty + i * 8) * C + c0 + tx];
  __syncthreads();
#pragma unroll
  for (int i = 0; i < 4; ++i)
    dst[zo + (long long)(c0 + ty + i * 8) * R + r0 + tx] = f2bf(t[tx][ty + i * 8]);
}

// ---------------- u[h,d]=sum_e Wq[h,d,e]*bk[h,e] (sel0) / v from Wk,bq (sel1) ----------------
__global__ __launch_bounds__(256) void k_uv(const float* __restrict__ Wq, const float* __restrict__ bk,
                                            const float* __restrict__ Wk, const float* __restrict__ bq,
                                            float* __restrict__ u, float* __restrict__ v) {
  const int sel = blockIdx.y;
  const float* W = sel ? Wk : Wq;
  const float* bb = sel ? bq : bk;
  float* dst = sel ? v : u;
  const int wave = threadIdx.x >> 6, lane = threadIdx.x & 63;
  const int idx = blockIdx.x * 4 + wave;
  const int h = idx >> 9, d = idx & 511;
  const float* wr = W + ((long long)h * 512 + d) * 512 + lane * 8;
  const float* br = bb + h * 512 + lane * 8;
  float s = 0.f;
#pragma unroll
  for (int k = 0; k < 8; ++k) s += wr[k] * br[k];
#pragma unroll
  for (int off = 32; off; off >>= 1) s += __shfl_xor(s, off);
  if (lane == 0) dst[h * 512 + d] = s;
}

// ---------------- c[h] = bq[h].bk[h] ----------------
__global__ __launch_bounds__(512) void k_bdot(const float* __restrict__ bq,
                                              const float* __restrict__ bk,
                                              float* __restrict__ c) {
  const int wave = threadIdx.x >> 6, lane = threadIdx.x & 63;
  const float* a = bq + wave * 512 + lane * 8;
  const float* b = bk + wave * 512 + lane * 8;
  float s = 0.f;
#pragma unroll
  for (int k = 0; k < 8; ++k) s += a[k] * b[k];
#pragma unroll
  for (int off = 32; off; off >>= 1) s += __shfl_xor(s, off);
  if (lane == 0) c[wave] = s;
}

// ---------------- rt[b*8+h][i] = in1[b,i,:].u[h,:] + c[h]; ct from in2,v ----------------
__global__ __launch_bounds__(256) void k_rtct(const float* __restrict__ in1, const float* __restrict__ in2,
                                              const float* __restrict__ u, const float* __restrict__ v,
                                              const float* __restrict__ cbuf,
                                              float* __restrict__ rt, float* __restrict__ ct) {
  const int sel = blockIdx.y;
  const float* src = sel ? in2 : in1;
  const float* vec = sel ? v : u;
  float* dst = sel ? ct : rt;
  const int row = blockIdx.x;
  __shared__ float x[512];
  const float* p = src + (long long)row * 512;
  x[threadIdx.x] = p[threadIdx.x];
  x[threadIdx.x + 256] = p[threadIdx.x + 256];
  __syncthreads();
  const int wave = threadIdx.x >> 6, lane = threadIdx.x & 63;
  const int b = row >> 10, i = row & 1023;
#pragma unroll
  for (int t = 0; t < 2; ++t) {
    const int h = wave * 2 + t;
    const float* wv = vec + h * 512;
    float s = 0.f;
#pragma unroll
    for (int k = 0; k < 8; ++k) s += x[lane + k * 64] * wv[lane + k * 64];
#pragma unroll
    for (int off = 32; off; off >>= 1) s += __shfl_xor(s, off);
    if (lane == 0)
      dst[((long long)(b * 8 + h)) * 1024 + i] = s + (sel ? 0.f : cbuf[h]);
  }
}

// ---------------- in-place row softmax over 1024 bf16, one wave per row ----------------
__global__ __launch_bounds__(256) void k_softmax_bf16(unsigned short* __restrict__ P) {
  const int wave = threadIdx.x >> 6, lane = threadIdx.x & 63;
  unsigned short* p = P + ((long long)blockIdx.x * 4 + wave) * 1024 + lane * 16;
  const b16x8 v0 = *(const b16x8*)p;
  const b16x8 v1 = *(const b16x8*)(p + 8);
  float f[16];
#pragma unroll
  for (int j = 0; j < 8; ++j) { f[j] = (float)v0[j]; f[8 + j] = (float)v1[j]; }
  float mx = f[0];
#pragma unroll
  for (int j = 1; j < 16; ++j) mx = fmaxf(mx, f[j]);
#pragma unroll
  for (int off = 32; off; off >>= 1) mx = fmaxf(mx, __shfl_xor(mx, off));
  float sum = 0.f;
#pragma unroll
  for (int j = 0; j < 16; ++j) { f[j] = __expf(f[j] - mx); sum += f[j]; }
#pragma unroll
  for (int off = 32; off; off >>= 1) sum += __shfl_xor(sum, off);
  const float inv = 1.f / sum;
  b16x8 o0, o1;
#pragma unroll
  for (int j = 0; j < 8; ++j) { o0[j] = (__bf16)(f[j] * inv); o1[j] = (__bf16)(f[8 + j] * inv); }
  *(b16x8*)p = o0;
  *(b16x8*)(p + 8) = o1;
}

// ---------------- old 128x128 GEMM (small Gt GEMM) ----------------
template <int OM>
__global__ __launch_bounds__(256) void k_gemm_bt(
    const unsigned short* __restrict__ A, const unsigned short* __restrict__ Bt,
    void* __restrict__ Cv, const float* __restrict__ bias,
    const float* __restrict__ rAdd, const float* __restrict__ cAdd,
    int K, int lda, int ldb, int ldc,
    int azs, int azm, long long azr,
    int bzs, int bzm, long long bzr,
    int czs, long long czr, int czm, int czc,
    int biasm, int bstr, int rstr, float scale) {
  __shared__ unsigned short lA[128 * 64];
  __shared__ unsigned short lB[128 * 64];
  const int tid = threadIdx.x, wave = tid >> 6, lane = tid & 63;
  const int z = blockIdx.z;
  const int m0 = blockIdx.y * 128, n0 = blockIdx.x * 128;
  const unsigned short* Az = A + (long long)((z >> azs) & azm) * azr + (long long)m0 * lda;
  const unsigned short* Bz = Bt + (long long)((z >> bzs) & bzm) * bzr + (long long)n0 * ldb;

  const int srow = wave * 32 + (lane >> 3);
  const int scol = (lane & 7) * 8;
  const unsigned short* ga = Az + (long long)srow * lda + scol;
  const unsigned short* gb = Bz + (long long)srow * ldb + scol;
  unsigned short* laBase = &lA[(wave * 32) * 64];
  unsigned short* lbBase = &lB[(wave * 32) * 64];

  f32x4 acc[4][4] = {};
  const int wr = (wave >> 1) * 64, wc = (wave & 1) * 64;
  const int fr = lane & 15, kq = (lane >> 4) * 8;

  for (int k0 = 0; k0 < K; k0 += 64) {
#pragma unroll
    for (int i = 0; i < 4; ++i) {
      gload_lds16(ga + (long long)(i * 8) * lda + k0, laBase + (i * 8) * 64);
      gload_lds16(gb + (long long)(i * 8) * ldb + k0, lbBase + (i * 8) * 64);
    }
    __syncthreads();
#pragma unroll
    for (int kk = 0; kk < 64; kk += 32) {
      b16x8 af[4], bf[4];
#pragma unroll
      for (int i = 0; i < 4; ++i)
        af[i] = *(const b16x8*)&lA[(wr + i * 16 + fr) * 64 + kk + kq];
#pragma unroll
      for (int j = 0; j < 4; ++j)
        bf[j] = *(const b16x8*)&lB[(wc + j * 16 + fr) * 64 + kk + kq];
#pragma unroll
      for (int i = 0; i < 4; ++i)
#pragma unroll
        for (int j = 0; j < 4; ++j)
          acc[i][j] = __builtin_amdgcn_mfma_f32_16x16x32_bf16(af[i], bf[j], acc[i][j], 0, 0, 0);
    }
    __syncthreads();
  }

  const long long coff = (long long)(z >> czs) * czr + (long long)(z & czm) * czc;
  const long long zr = (long long)z * rstr;
  const int rr = (lane >> 4) * 4;
#pragma unroll
  for (int j = 0; j < 4; ++j) {
    const int col = n0 + wc + j * 16 + fr;
    const float bval = bias ? bias[(long long)(z & biasm) * bstr + col] : 0.f;
    const float ca = cAdd ? cAdd[zr + col] : 0.f;
#pragma unroll
    for (int i = 0; i < 4; ++i) {
#pragma unroll
      for (int r = 0; r < 4; ++r) {
        const int row = m0 + wr + i * 16 + rr + r;
        const float ra = rAdd ? rAdd[zr + row] : 0.f;
        const float val = (acc[i][j][r] + ra + ca) * scale + bval;
        if constexpr (OM == 1) {
          ((unsigned short*)Cv)[coff + (long long)row * ldc + col] = f2bf(val);
        } else if constexpr (OM == 2) {
          ((unsigned short*)Cv)[coff + (long long)col * ldc + row] = f2bf(val);
        } else {
          ((float*)Cv)[coff + (long long)row * ldc + col] = val;
        }
      }
    }
  }
}

// ================= 256x256 GEMM, LDS-coalesced epilogue =================
// SB=0: R6 double-buffered (128 KiB LDS, 1 block/CU, stage-early + vmcnt(8)).
// SB=1: single-buffered (64 KiB LDS -> 2 independent blocks/CU; per tile:
//       stage -> vmcnt(0)+barrier -> compute -> barrier; the drain is covered
//       by the co-resident block's compute phase, m97/m114-style).
#define STAGE_A8(nb, koff, i)                                  \
  gload_lds16(gaL + (long long)((i) * 8) * lda + (koff) + scol, \
              &sh[nb][(wid * 32 + (i) * 8) * 64])
#define STAGE_B8(nb, koff, i)                                  \
  gload_lds16(gbL + (long long)((i) * 8) * ldb + (koff) + scol, \
              &sh[SB ? 1 : 2 + (nb)][(wid * 32 + (i) * 8) * 64])

template <int OM, int SB>
__global__ __launch_bounds__(512, 2) void k_gemm8p(
    const unsigned short* __restrict__ A, const unsigned short* __restrict__ Bt,
    void* __restrict__ Cv, const float* __restrict__ bias,
    const float* __restrict__ rAdd, const float* __restrict__ cAdd,
    int K, int lda, int ldb, int ldc,
    int azs, int azm, long long azr,
    int bzs, int bzm, long long bzr,
    int czs, long long czr, int czm, int czc,
    int biasm, int bstr, int rstr, float scale, int kzm, int kzr) {
  __shared__ unsigned short sh[SB ? 2 : 4][256 * 64];
  const int tid = threadIdx.x, wid = tid >> 6, lane = tid & 63;
  const int wm = wid >> 2, wn = wid & 3;

  // XCD-chunked bijective block swizzle (nwg multiple of 8 for all uses)
  const int gx = gridDim.x, gy = gridDim.y;
  const int nwg = gx * gy * gridDim.z;
  const int bidL = blockIdx.x + gx * (blockIdx.y + gy * blockIdx.z);
  const int q8 = nwg >> 3;
  const int idx = (bidL & 7) * q8 + (bidL >> 3);
  const int bx = idx % gx;
  const int rem = idx / gx;
  const int by = rem % gy;
  const int z = rem / gy;

  const int m0 = by * 256, n0 = bx * 256;
  const int kstart = (z & kzm) * kzr;
  const unsigned short* Az = A + (long long)((z >> azs) & azm) * azr + (long long)m0 * lda + kstart;
  const unsigned short* Bz = Bt + (long long)((z >> bzs) & bzm) * bzr + (long long)n0 * ldb + kstart;

  const int scol = (((lane & 7) ^ ((lane >> 3) & 7)) << 3);
  const unsigned short* gaL = Az + (long long)(wid * 32 + (lane >> 3)) * lda;
  const unsigned short* gbL = Bz + (long long)(wid * 32 + (lane >> 3)) * ldb;

  const int fr = lane & 15, kq = (lane >> 4) * 8;
  const int fsw = (fr & 7) << 3;
  const int rc0 = kq ^ fsw;
  const int rc1 = (32 + kq) ^ fsw;
  const int aBase = (wm * 128 + fr) * 64;
  const int bBase = (wn * 64 + fr) * 64;

  f32x4 acc[8][4] = {};
  b16x8 afr[4][2], bfr[4][2];
  const int NT = K >> 6;

  if constexpr (!SB) {
#pragma unroll
    for (int i = 0; i < 4; ++i) { STAGE_A8(0, 0, i); STAGE_B8(0, 0, i); }
  }

  for (int kt = 0; kt < NT; ++kt) {
    const int cur = SB ? 0 : (kt & 1);
    const int nb = cur ^ 1;
    if constexpr (SB) {
      const int ko = kt << 6;
#pragma unroll
      for (int i = 0; i < 4; ++i) { STAGE_A8(0, ko, i); STAGE_B8(0, ko, i); }
      asm volatile("s_waitcnt vmcnt(0)" ::: "memory");
    } else {
      if (kt + 1 < NT) {
        const int ko = (kt + 1) << 6;
#pragma unroll
        for (int i = 0; i < 4; ++i) { STAGE_A8(nb, ko, i); STAGE_B8(nb, ko, i); }
        asm volatile("s_waitcnt vmcnt(8)" ::: "memory");
      } else {
        asm volatile("s_waitcnt vmcnt(0)" ::: "memory");
      }
    }
    __builtin_amdgcn_s_barrier();
    __builtin_amdgcn_sched_barrier(0);
    const int aI = SB ? 0 : cur;
    const int bI = SB ? 1 : 2 + cur;

    // Q0
#pragma unroll
    for (int i = 0; i < 4; ++i) {
      afr[i][0] = *(const b16x8*)&sh[aI][aBase + i * 1024 + rc0];
      afr[i][1] = *(const b16x8*)&sh[aI][aBase + i * 1024 + rc1];
    }
#pragma unroll
    for (int j = 0; j < 2; ++j) {
      bfr[j][0] = *(const b16x8*)&sh[bI][bBase + j * 1024 + rc0];
      bfr[j][1] = *(const b16x8*)&sh[bI][bBase + j * 1024 + rc1];
    }
    __builtin_amdgcn_s_setprio(1);
#pragma unroll
    for (int t = 0; t < 2; ++t)
#pragma unroll
      for (int i = 0; i < 4; ++i)
#pragma unroll
        for (int j = 0; j < 2; ++j)
          acc[i][j] = __builtin_amdgcn_mfma_f32_16x16x32_bf16(afr[i][t], bfr[j][t], acc[i][j], 0, 0, 0);
    __builtin_amdgcn_s_setprio(0);
    // Q1
#pragma unroll
    for (int j = 2; j < 4; ++j) {
      bfr[j][0] = *(const b16x8*)&sh[bI][bBase + j * 1024 + rc0];
      bfr[j][1] = *(const b16x8*)&sh[bI][bBase + j * 1024 + rc1];
    }
    __builtin_amdgcn_s_setprio(1);
#pragma unroll
    for (int t = 0; t < 2; ++t)
#pragma unroll
      for (int i = 0; i < 4; ++i)
#pragma unroll
        for (int j = 2; j < 4; ++j)
          acc[i][j] = __builtin_amdgcn_mfma_f32_16x16x32_bf16(afr[i][t], bfr[j][t], acc[i][j], 0, 0, 0);
    __builtin_amdgcn_s_setprio(0);
    // Q2
#pragma unroll
    for (int i = 0; i < 4; ++i) {
      afr[i][0] = *(const b16x8*)&sh[aI][aBase + (i + 4) * 1024 + rc0];
      afr[i][1] = *(const b16x8*)&sh[aI][aBase + (i + 4) * 1024 + rc1];
    }
    __builtin_amdgcn_s_setprio(1);
#pragma unroll
    for (int t = 0; t < 2; ++t)
#pragma unroll
      for (int i = 0; i < 4; ++i)
#pragma unroll
        for (int j = 0; j < 2; ++j)
          acc[i + 4][j] = __builtin_amdgcn_mfma_f32_16x16x32_bf16(afr[i][t], bfr[j][t], acc[i + 4][j], 0, 0, 0);
    __builtin_amdgcn_s_setprio(0);
    // Q3
    __builtin_amdgcn_s_setprio(1);
#pragma unroll
    for (int t = 0; t < 2; ++t)
#pragma unroll
      for (int i = 0; i < 4; ++i)
#pragma unroll
        for (int j = 2; j < 4; ++j)
          acc[i + 4][j] = __builtin_amdgcn_mfma_f32_16x16x32_bf16(afr[i][t], bfr[j][t], acc[i + 4][j], 0, 0, 0);
    __builtin_amdgcn_s_setprio(0);

    __builtin_amdgcn_s_barrier();
  }

  // ---------------- LDS-coalesced epilogue ----------------
  const long long coff = (long long)(z >> czs) * czr + (long long)(z & czm) * czc;
  const long long zr = (long long)z * rstr;
  const int rr = (lane >> 4) * 4;
  unsigned short* flat = &sh[0][0];

  if constexpr (OM == 1 || OM == 2) {
    const long long rbase = (OM == 2) ? (long long)n0 : (long long)m0;
    const long long cbase = (OM == 2) ? (long long)m0 : (long long)n0;
    unsigned short* Cb = (unsigned short*)Cv;
    if constexpr (SB) {
      // two 128-row halves of the output image (64 KiB each)
#pragma unroll
      for (int half = 0; half < 2; ++half) {
        const bool mine = (OM == 1) ? (wm == half) : ((wn >> 1) == half);
        if (mine) {
#pragma unroll
          for (int j = 0; j < 4; ++j) {
            const int col = n0 + wn * 64 + j * 16 + fr;
            const float bval = bias ? bias[(long long)(z & biasm) * bstr + col] : 0.f;
            const float ca = cAdd ? cAdd[zr + col] : 0.f;
#pragma unroll
            for (int i = 0; i < 8; ++i) {
#pragma unroll
              for (int r = 0; r < 4; ++r) {
                const int row = m0 + wm * 128 + i * 16 + rr + r;
                const float ra = rAdd ? rAdd[zr + row] : 0.f;
                const float val = (acc[i][j][r] + ra + ca) * scale + bval;
                const int rowL = wm * 128 + i * 16 + rr + r;
                const int colL = wn * 64 + j * 16 + fr;
                const int sR = (OM == 2) ? colL : rowL;
                const int sC = (OM == 2) ? rowL : colL;
                const int lR = sR - half * 128;
                flat[lR * 256 + (sC ^ ((lR & 7) << 3))] = f2bf(val);
              }
            }
          }
        }
        __builtin_amdgcn_s_barrier();
#pragma unroll
        for (int it = 0; it < 8; ++it) {
          const int t = it * 512 + tid;
          const int R = t >> 5;
          const int Cq = t & 31;
          const int q = Cq ^ (R & 7);
          const b16x8 v = *(const b16x8*)&flat[R * 256 + q * 8];
          *(b16x8*)(Cb + coff + (rbase + half * 128 + R) * ldc + cbase + Cq * 8) = v;
        }
        __builtin_amdgcn_s_barrier();
      }
    } else {
#pragma unroll
      for (int j = 0; j < 4; ++j) {
        const int col = n0 + wn * 64 + j * 16 + fr;
        const float bval = bias ? bias[(long long)(z & biasm) * bstr + col] : 0.f;
        const float ca = cAdd ? cAdd[zr + col] : 0.f;
#pragma unroll
        for (int i = 0; i < 8; ++i) {
#pragma unroll
          for (int r = 0; r < 4; ++r) {
            const int row = m0 + wm * 128 + i * 16 + rr + r;
            const float ra = rAdd ? rAdd[zr + row] : 0.f;
            const float val = (acc[i][j][r] + ra + ca) * scale + bval;
            const int rowL = wm * 128 + i * 16 + rr + r;
            const int colL = wn * 64 + j * 16 + fr;
            const int sR = (OM == 2) ? colL : rowL;
            const int sC = (OM == 2) ? rowL : colL;
            flat[sR * 256 + (sC ^ ((sR & 7) << 3))] = f2bf(val);
          }
        }
      }
      __builtin_amdgcn_s_barrier();
#pragma unroll
      for (int it = 0; it < 16; ++it) {
        const int t = it * 512 + tid;
        const int R = t >> 5;
        const int Cq = t & 31;
        const int q = Cq ^ (R & 7);
        const b16x8 v = *(const b16x8*)&flat[R * 256 + q * 8];
        *(b16x8*)(Cb + coff + (rbase + R) * ldc + cbase + Cq * 8) = v;
      }
    }
  } else if constexpr (OM == 0 && !SB) {
    float* fflat = (float*)flat;
    float* Cf = (float*)Cv;
#pragma unroll
    for (int half = 0; half < 2; ++half) {
      if (wm == half) {
#pragma unroll
        for (int j = 0; j < 4; ++j) {
          const int col = n0 + wn * 64 + j * 16 + fr;
          const float bval = bias ? bias[(long long)(z & biasm) * bstr + col] : 0.f;
          const float ca = cAdd ? cAdd[zr + col] : 0.f;
#pragma unroll
          for (int i = 0; i < 8; ++i) {
#pragma unroll
            for (int r = 0; r < 4; ++r) {
              const int row = m0 + wm * 128 + i * 16 + rr + r;
              const float ra = rAdd ? rAdd[zr + row] : 0.f;
              const float val = (acc[i][j][r] + ra + ca) * scale + bval;
              const int Rl = i * 16 + rr + r;
              const int Cl = wn * 64 + j * 16 + fr;
              fflat[Rl * 256 + (Cl ^ ((Rl & 7) << 2))] = val;
            }
          }
        }
      }
      __builtin_amdgcn_s_barrier();
#pragma unroll
      for (int it = 0; it < 16; ++it) {
        const int t = it * 512 + tid;
        const int R = t >> 6;
        const int Cq = t & 63;
        const int q = Cq ^ (R & 7);
        const float4 v = *(const float4*)&fflat[R * 256 + q * 4];
        *(float4*)(Cf + coff + (long long)(m0 + half * 128 + R) * ldc + n0 + Cq * 4) = v;
      }
      __builtin_amdgcn_s_barrier();
    }
  }
}

// ---------------- out = sum of 4 f32 partials + bias(per 512 cols) ----------------
__global__ __launch_bounds__(256) void k_reduce4(const float* __restrict__ p,
                                                 const float* __restrict__ bo,
                                                 float* __restrict__ out) {
  const long long i = (long long)blockIdx.x * 256 + threadIdx.x;
  const float4* p4 = (const float4*)p;
  float4 a = p4[i], b = p4[i + 1048576], c = p4[i + 2097152], d = p4[i + 3145728];
  const float4 bb = ((const float4*)bo)[i & 127];
  float4 o;
  o.x = a.x + b.x + c.x + d.x + bb.x;
  o.y = a.y + b.y + c.y + d.y + bb.y;
  o.z = a.z + b.z + c.z + d.z + bb.z;
  o.w = a.w + b.w + c.w + d.w + bb.w;
  ((float4*)out)[i] = o;
}

extern "C" void kernel_launch(void* const* d_in, const int* in_sizes, int n_in,
                              void* d_out, int out_size, void* d_ws, size_t ws_size,
                              hipStream_t stream) {
  const float* in1 = (const float*)d_in[0];
  const float* in2 = (const float*)d_in[1];
  const float* in3 = (const float*)d_in[2];
  const float* Wq = (const float*)d_in[3];
  const float* bq = (const float*)d_in[4];
  const float* Wk = (const float*)d_in[5];
  const float* bk = (const float*)d_in[6];
  const float* Wv = (const float*)d_in[7];
  const float* bv = (const float*)d_in[8];
  const float* Wo = (const float*)d_in[9];
  const float* bo = (const float*)d_in[10];

  const long long MB = 1024 * 1024;
  typedef unsigned short us;
  unsigned char* w = (unsigned char*)d_ws;
  us* in2b = (us*)(w);                 // 8 MB
  us* Tbuf = (us*)(w + 8 * MB);        // 64 MB (T, then concat per-chunk)
  us* Vt = (us*)(w + 72 * MB);         // 64 MB (then out-proj partials)
  us* wvt = (us*)(w + 136 * MB);       // 4 MB
  us* wot = (us*)(w + 140 * MB);       // 4 MB
  us* scb = (us*)(w + 144 * MB);       // 64 MB (scores/P bf16, in-place)
  us* in1b = (us*)(w + 208 * MB);      // 8 MB
  us* in3b = (us*)(w + 216 * MB);      // 8 MB
  us* wqb = (us*)(w + 224 * MB);       // 4 MB
  us* wkb = (us*)(w + 228 * MB);       // 4 MB
  us* Gt = (us*)(w + 232 * MB);        // 4 MB
  float* rt = (float*)(w + 236 * MB);  // 256 KB
  float* ct = (float*)(w + 236 * MB + (256 << 10));
  float* ubuf = (float*)(w + 237 * MB);
  float* vbuf = (float*)(w + 237 * MB + (16 << 10));
  float* cbuf = (float*)(w + 237 * MB + (32 << 10));
  float* partials = (float*)(w + 72 * MB);  // 64 MB over Vt (dead by then)
  if ((long long)ws_size < 238 * MB) return;

  const float iscale = 0.04419417382415922f;  // 1/sqrt(512)
  const long long SD = 1024 * 512;            // 524288

  // conversions / transposes
  k_conv_bf16<<<4096, 256, 0, stream>>>(in1, in1b, 1048576);
  k_conv_bf16<<<4096, 256, 0, stream>>>(in2, in2b, 1048576);
  k_conv_bf16<<<4096, 256, 0, stream>>>(in3, in3b, 1048576);
  k_conv_bf16<<<2048, 256, 0, stream>>>(Wq, wqb, 524288);
  k_conv_bf16<<<2048, 256, 0, stream>>>(Wk, wkb, 524288);
  k_transpose_bf16<<<dim3(16, 16, 8), dim3(32, 8), 0, stream>>>(Wv, wvt, 512, 512);
  k_transpose_bf16<<<dim3(16, 128, 1), dim3(32, 8), 0, stream>>>(Wo, wot, 4096, 512);

  // bias cross-terms
  k_uv<<<dim3(1024, 2), 256, 0, stream>>>(Wq, bk, Wk, bq, ubuf, vbuf);
  k_bdot<<<1, 512, 0, stream>>>(bq, bk, cbuf);
  k_rtct<<<dim3(8192, 2), 256, 0, stream>>>(in1, in2, ubuf, vbuf, cbuf, rt, ct);

  // Gt[h] = Wk[h] Wq[h]^T  (small; old kernel)
  k_gemm_bt<1><<<dim3(4, 4, 8), 256, 0, stream>>>(
      wkb, wqb, Gt, nullptr, nullptr, nullptr, 512, 512, 512, 512,
      0, 7, 262144LL, 0, 7, 262144LL, 0, 262144LL, 0, 0, 0, 0, 0, 1.f);

  // T[z=b*8+h] = X1[b] G[h]   [64][1024][512] bf16   (SB=1: 2 blocks/CU)
  k_gemm8p<1, 1><<<dim3(2, 4, 64), 512, 0, stream>>>(
      in1b, Gt, Tbuf, nullptr, nullptr, nullptr, 512, 512, 512, 512,
      3, 7, SD, 0, 7, 262144LL, 0, SD, 0, 0, 0, 0, 0, 1.f, 0, 0);

  // V-proj transposed: Vt[z][e][s]  [64][512][1024] bf16, +bv   (SB=1)
  k_gemm8p<2, 1><<<dim3(2, 4, 64), 512, 0, stream>>>(
      in3b, wvt, Vt, bv, nullptr, nullptr, 512, 512, 512, 1024,
      3, 7, SD, 0, 7, 262144LL, 0, SD, 0, 0, 7, 512, 0, 1.f, 0, 0);

  // attention in 2 chunks of 4 batches (32 heads each)
  for (int c = 0; c < 2; ++c) {
    // scores[zz][i][j] = (T X2^T + rt + ct) * iscale -> bf16   (SB=0 control)
    k_gemm8p<1, 0><<<dim3(4, 4, 32), 512, 0, stream>>>(
        Tbuf + (long long)c * 32 * SD, in2b + (long long)c * 4 * SD, scb, nullptr,
        rt + c * 32768, ct + c * 32768, 512, 512, 512, 1024,
        0, 31, SD, 3, 3, SD, 0, 1048576LL, 0, 0, 0, 0, 1024, iscale, 0, 0);
    k_softmax_bf16<<<8192, 256, 0, stream>>>(scb);
    // heads -> concat[(c*4+b')*1024 + i][h*512 + e]
    k_gemm8p<1, 0><<<dim3(2, 4, 32), 512, 0, stream>>>(
        scb, Vt + (long long)c * 32 * SD, Tbuf + (long long)c * 16777216LL, nullptr,
        nullptr, nullptr, 1024, 1024, 1024, 4096,
        0, 31, 1048576LL, 0, 31, SD, 3, 4194304LL, 7, 512, 0, 0, 0, 1.f, 0, 0);
  }

  // out-proj split-K=4: partials[ks] = concat[:, ks*1024:+1024] @ wot[:, same]^T
  k_gemm8p<0, 0><<<dim3(2, 32, 4), 512, 0, stream>>>(
      Tbuf, wot, partials, nullptr, nullptr, nullptr, 1024, 4096, 4096, 512,
      0, 0, 0, 0, 0, 0, 0, 4194304LL, 0, 0, 0, 0, 0, 1.f, 3, 1024);
  k_reduce4<<<4096, 256, 0, stream>>>(partials, bo, (float*)d_out);
}

// Round 10
// 509.026 us; speedup vs baseline: 1.0150x; 1.0150x over previous
//
#include <hip/hip_runtime.h>
#include <hip/hip_bf16.h>

#define DEV static __device__ __forceinline__

typedef float f32x4 __attribute__((ext_vector_type(4)));
typedef __bf16 b16x8 __attribute__((ext_vector_type(8)));

DEV unsigned short f2bf(float f) {
  union { __hip_bfloat16 h; unsigned short u; } cv;
  cv.h = __float2bfloat16(f);
  return cv.u;
}

DEV void gload_lds16(const unsigned short* g, unsigned short* l) {
  __builtin_amdgcn_global_load_lds(
      (__attribute__((address_space(1))) void*)g,
      (__attribute__((address_space(3))) void*)l, 16, 0, 0);
}

// ---------------- f32 -> bf16 elementwise ----------------
__global__ __launch_bounds__(256) void k_conv_bf16(const float* __restrict__ src,
                                                   unsigned short* __restrict__ dst,
                                                   long long n4) {
  long long i = (long long)blockIdx.x * 256 + threadIdx.x;
  if (i >= n4) return;
  const float4 v = ((const float4*)src)[i];
  ushort4 o;
  o.x = f2bf(v.x); o.y = f2bf(v.y); o.z = f2bf(v.z); o.w = f2bf(v.w);
  ((ushort4*)dst)[i] = o;
}

// ---------------- f32 [z][R][C] -> bf16 [z][C][R] ----------------
__global__ __launch_bounds__(256) void k_transpose_bf16(const float* __restrict__ src,
                                                        unsigned short* __restrict__ dst,
                                                        int R, int C) {
  __shared__ float t[32][33];
  const long long zo = (long long)blockIdx.z * R * C;
  const int c0 = blockIdx.x * 32, r0 = blockIdx.y * 32;
  const int tx = threadIdx.x, ty = threadIdx.y;
#pragma unroll
  for (int i = 0; i < 4; ++i)
    t[ty + i * 8][tx] = src[zo + (long long)(r0 + ty + i * 8) * C + c0 + tx];
  __syncthreads();
#pragma unroll
  for (int i = 0; i < 4; ++i)
    dst[zo + (long long)(c0 + ty + i * 8) * R + r0 + tx] = f2bf(t[tx][ty + i * 8]);
}

// ---------------- u[h,d]=sum_e Wq[h,d,e]*bk[h,e] (sel0) / v from Wk,bq (sel1) ----------------
__global__ __launch_bounds__(256) void k_uv(const float* __restrict__ Wq, const float* __restrict__ bk,
                                            const float* __restrict__ Wk, const float* __restrict__ bq,
                                            float* __restrict__ u, float* __restrict__ v) {
  const int sel = blockIdx.y;
  const float* W = sel ? Wk : Wq;
  const float* bb = sel ? bq : bk;
  float* dst = sel ? v : u;
  const int wave = threadIdx.x >> 6, lane = threadIdx.x & 63;
  const int idx = blockIdx.x * 4 + wave;
  const int h = idx >> 9, d = idx & 511;
  const float* wr = W + ((long long)h * 512 + d) * 512 + lane * 8;
  const float* br = bb + h * 512 + lane * 8;
  float s = 0.f;
#pragma unroll
  for (int k = 0; k < 8; ++k) s += wr[k] * br[k];
#pragma unroll
  for (int off = 32; off; off >>= 1) s += __shfl_xor(s, off);
  if (lane == 0) dst[h * 512 + d] = s;
}

// ---------------- c[h] = bq[h].bk[h] ----------------
__global__ __launch_bounds__(512) void k_bdot(const float* __restrict__ bq,
                                              const float* __restrict__ bk,
                                              float* __restrict__ c) {
  const int wave = threadIdx.x >> 6, lane = threadIdx.x & 63;
  const float* a = bq + wave * 512 + lane * 8;
  const float* b = bk + wave * 512 + lane * 8;
  float s = 0.f;
#pragma unroll
  for (int k = 0; k < 8; ++k) s += a[k] * b[k];
#pragma unroll
  for (int off = 32; off; off >>= 1) s += __shfl_xor(s, off);
  if (lane == 0) c[wave] = s;
}

// ---------------- rt[b*8+h][i] = in1[b,i,:].u[h,:] + c[h]; ct from in2,v ----------------
__global__ __launch_bounds__(256) void k_rtct(const float* __restrict__ in1, const float* __restrict__ in2,
                                              const float* __restrict__ u, const float* __restrict__ v,
                                              const float* __restrict__ cbuf,
                                              float* __restrict__ rt, float* __restrict__ ct) {
  const int sel = blockIdx.y;
  const float* src = sel ? in2 : in1;
  const float* vec = sel ? v : u;
  float* dst = sel ? ct : rt;
  const int row = blockIdx.x;
  __shared__ float x[512];
  const float* p = src + (long long)row * 512;
  x[threadIdx.x] = p[threadIdx.x];
  x[threadIdx.x + 256] = p[threadIdx.x + 256];
  __syncthreads();
  const int wave = threadIdx.x >> 6, lane = threadIdx.x & 63;
  const int b = row >> 10, i = row & 1023;
#pragma unroll
  for (int t = 0; t < 2; ++t) {
    const int h = wave * 2 + t;
    const float* wv = vec + h * 512;
    float s = 0.f;
#pragma unroll
    for (int k = 0; k < 8; ++k) s += x[lane + k * 64] * wv[lane + k * 64];
#pragma unroll
    for (int off = 32; off; off >>= 1) s += __shfl_xor(s, off);
    if (lane == 0)
      dst[((long long)(b * 8 + h)) * 1024 + i] = s + (sel ? 0.f : cbuf[h]);
  }
}

// ---------------- in-place row softmax over 1024 bf16, one wave per row ----------------
__global__ __launch_bounds__(256) void k_softmax_bf16(unsigned short* __restrict__ P) {
  const int wave = threadIdx.x >> 6, lane = threadIdx.x & 63;
  unsigned short* p = P + ((long long)blockIdx.x * 4 + wave) * 1024 + lane * 16;
  const b16x8 v0 = *(const b16x8*)p;
  const b16x8 v1 = *(const b16x8*)(p + 8);
  float f[16];
#pragma unroll
  for (int j = 0; j < 8; ++j) { f[j] = (float)v0[j]; f[8 + j] = (float)v1[j]; }
  float mx = f[0];
#pragma unroll
  for (int j = 1; j < 16; ++j) mx = fmaxf(mx, f[j]);
#pragma unroll
  for (int off = 32; off; off >>= 1) mx = fmaxf(mx, __shfl_xor(mx, off));
  float sum = 0.f;
#pragma unroll
  for (int j = 0; j < 16; ++j) { f[j] = __expf(f[j] - mx); sum += f[j]; }
#pragma unroll
  for (int off = 32; off; off >>= 1) sum += __shfl_xor(sum, off);
  const float inv = 1.f / sum;
  b16x8 o0, o1;
#pragma unroll
  for (int j = 0; j < 8; ++j) { o0[j] = (__bf16)(f[j] * inv); o1[j] = (__bf16)(f[8 + j] * inv); }
  *(b16x8*)p = o0;
  *(b16x8*)(p + 8) = o1;
}

// ---------------- old 128x128 GEMM (small Gt GEMM) ----------------
template <int OM>
__global__ __launch_bounds__(256) void k_gemm_bt(
    const unsigned short* __restrict__ A, const unsigned short* __restrict__ Bt,
    void* __restrict__ Cv, const float* __restrict__ bias,
    const float* __restrict__ rAdd, const float* __restrict__ cAdd,
    int K, int lda, int ldb, int ldc,
    int azs, int azm, long long azr,
    int bzs, int bzm, long long bzr,
    int czs, long long czr, int czm, int czc,
    int biasm, int bstr, int rstr, float scale) {
  __shared__ unsigned short lA[128 * 64];
  __shared__ unsigned short lB[128 * 64];
  const int tid = threadIdx.x, wave = tid >> 6, lane = tid & 63;
  const int z = blockIdx.z;
  const int m0 = blockIdx.y * 128, n0 = blockIdx.x * 128;
  const unsigned short* Az = A + (long long)((z >> azs) & azm) * azr + (long long)m0 * lda;
  const unsigned short* Bz = Bt + (long long)((z >> bzs) & bzm) * bzr + (long long)n0 * ldb;

  const int srow = wave * 32 + (lane >> 3);
  const int scol = (lane & 7) * 8;
  const unsigned short* ga = Az + (long long)srow * lda + scol;
  const unsigned short* gb = Bz + (long long)srow * ldb + scol;
  unsigned short* laBase = &lA[(wave * 32) * 64];
  unsigned short* lbBase = &lB[(wave * 32) * 64];

  f32x4 acc[4][4] = {};
  const int wr = (wave >> 1) * 64, wc = (wave & 1) * 64;
  const int fr = lane & 15, kq = (lane >> 4) * 8;

  for (int k0 = 0; k0 < K; k0 += 64) {
#pragma unroll
    for (int i = 0; i < 4; ++i) {
      gload_lds16(ga + (long long)(i * 8) * lda + k0, laBase + (i * 8) * 64);
      gload_lds16(gb + (long long)(i * 8) * ldb + k0, lbBase + (i * 8) * 64);
    }
    __syncthreads();
#pragma unroll
    for (int kk = 0; kk < 64; kk += 32) {
      b16x8 af[4], bf[4];
#pragma unroll
      for (int i = 0; i < 4; ++i)
        af[i] = *(const b16x8*)&lA[(wr + i * 16 + fr) * 64 + kk + kq];
#pragma unroll
      for (int j = 0; j < 4; ++j)
        bf[j] = *(const b16x8*)&lB[(wc + j * 16 + fr) * 64 + kk + kq];
#pragma unroll
      for (int i = 0; i < 4; ++i)
#pragma unroll
        for (int j = 0; j < 4; ++j)
          acc[i][j] = __builtin_amdgcn_mfma_f32_16x16x32_bf16(af[i], bf[j], acc[i][j], 0, 0, 0);
    }
    __syncthreads();
  }

  const long long coff = (long long)(z >> czs) * czr + (long long)(z & czm) * czc;
  const long long zr = (long long)z * rstr;
  const int rr = (lane >> 4) * 4;
#pragma unroll
  for (int j = 0; j < 4; ++j) {
    const int col = n0 + wc + j * 16 + fr;
    const float bval = bias ? bias[(long long)(z & biasm) * bstr + col] : 0.f;
    const float ca = cAdd ? cAdd[zr + col] : 0.f;
#pragma unroll
    for (int i = 0; i < 4; ++i) {
#pragma unroll
      for (int r = 0; r < 4; ++r) {
        const int row = m0 + wr + i * 16 + rr + r;
        const float ra = rAdd ? rAdd[zr + row] : 0.f;
        const float val = (acc[i][j][r] + ra + ca) * scale + bval;
        if constexpr (OM == 1) {
          ((unsigned short*)Cv)[coff + (long long)row * ldc + col] = f2bf(val);
        } else if constexpr (OM == 2) {
          ((unsigned short*)Cv)[coff + (long long)col * ldc + row] = f2bf(val);
        } else {
          ((float*)Cv)[coff + (long long)row * ldc + col] = val;
        }
      }
    }
  }
}

// ================= 128x256 BK=32 GEMM, 2 blocks/CU (k_g32) =================
// 8 waves of 64x64 (acc 64 VGPR), LDS 48 KiB (A dbuf 2x8K + B dbuf 2x16K),
// stage-early double-buffer + vmcnt(3) counted wait, 1 barrier pair/tile.
// 2 blocks/CU: one block's prologue+epilogue/store-drain overlaps the other's
// K-loop. BK=32 quad swizzle q^(row&3) (residual 4-way, sub-dominant).
template <int OM>
__global__ __launch_bounds__(512, 4) void k_g32(
    const unsigned short* __restrict__ A, const unsigned short* __restrict__ Bt,
    void* __restrict__ Cv, const float* __restrict__ bias,
    const float* __restrict__ rAdd, const float* __restrict__ cAdd,
    int K, int lda, int ldb, int ldc,
    int azs, int azm, long long azr,
    int bzs, int bzm, long long bzr,
    int czs, long long czr, int czm, int czc,
    int biasm, int bstr, int rstr, float scale) {
  __shared__ unsigned short sh[24576];  // [0:4K)=A0 [4K:8K)=A1 [8K:16K)=B0 [16K:24K)=B1
  const int tid = threadIdx.x, wid = tid >> 6, lane = tid & 63;
  const int wm = wid >> 2, wn = wid & 3;

  // XCD-chunked bijective block swizzle (nwg multiple of 8 for all uses)
  const int gx = gridDim.x, gy = gridDim.y;
  const int nwg = gx * gy * gridDim.z;
  const int bidL = blockIdx.x + gx * (blockIdx.y + gy * blockIdx.z);
  const int q8 = nwg >> 3;
  const int idx = (bidL & 7) * q8 + (bidL >> 3);
  const int bx = idx % gx;
  const int rem = idx / gx;
  const int by = rem % gy;
  const int z = rem / gy;

  const int m0 = by * 128, n0 = bx * 256;
  const unsigned short* Az = A + (long long)((z >> azs) & azm) * azr + (long long)m0 * lda;
  const unsigned short* Bz = Bt + (long long)((z >> bzs) & bzm) * bzr + (long long)n0 * ldb;

  // staging: A rows 128 -> wave stages rows wid*16..+16 (1 inst); B rows 256 ->
  // wave stages wid*32..+32 (2 insts). src col quad pre-swizzled: (l&3)^((l>>2)&3)
  const int scol = (((lane & 3) ^ ((lane >> 2) & 3)) << 3);
  const unsigned short* gaL = Az + (long long)(wid * 16 + (lane >> 2)) * lda + scol;
  const unsigned short* gbL = Bz + (long long)(wid * 32 + (lane >> 2)) * ldb + scol;

  // frag reads: row base + fr, col quad (l>>4)^(fr&3)
  const int fr = lane & 15;
  const int rq = ((lane >> 4) ^ (fr & 3)) << 3;
  f32x4 acc[4][4] = {};
  b16x8 afr[4], bfr[4];
  const int NT = K >> 5;

  // prologue: stage tile 0 into buf 0
  gload_lds16(gaL, &sh[(wid * 16) * 32]);
  gload_lds16(gbL, &sh[8192 + (wid * 32) * 32]);
  gload_lds16(gbL + (long long)16 * ldb, &sh[8192 + (wid * 32 + 16) * 32]);

  for (int kt = 0; kt < NT; ++kt) {
    const int cur = kt & 1, nb = cur ^ 1;
    if (kt + 1 < NT) {
      const int ko = (kt + 1) << 5;
      gload_lds16(gaL + ko, &sh[nb * 4096 + (wid * 16) * 32]);
      gload_lds16(gbL + ko, &sh[8192 + nb * 8192 + (wid * 32) * 32]);
      gload_lds16(gbL + (long long)16 * ldb + ko, &sh[8192 + nb * 8192 + (wid * 32 + 16) * 32]);
      asm volatile("s_waitcnt vmcnt(3)" ::: "memory");  // tile kt's 3 landed
    } else {
      asm volatile("s_waitcnt vmcnt(0)" ::: "memory");
    }
    __builtin_amdgcn_s_barrier();
    __builtin_amdgcn_sched_barrier(0);

    const int aO = cur * 4096, bO = 8192 + cur * 8192;
#pragma unroll
    for (int i = 0; i < 4; ++i)
      afr[i] = *(const b16x8*)&sh[aO + (wm * 64 + i * 16 + fr) * 32 + rq];
#pragma unroll
    for (int j = 0; j < 4; ++j)
      bfr[j] = *(const b16x8*)&sh[bO + (wn * 64 + j * 16 + fr) * 32 + rq];
    __builtin_amdgcn_s_setprio(1);
#pragma unroll
    for (int i = 0; i < 4; ++i)
#pragma unroll
      for (int j = 0; j < 4; ++j)
        acc[i][j] = __builtin_amdgcn_mfma_f32_16x16x32_bf16(afr[i], bfr[j], acc[i][j], 0, 0, 0);
    __builtin_amdgcn_s_setprio(0);

    __builtin_amdgcn_s_barrier();  // buf[cur] free for next-iter staging
  }

  // -------- LDS-coalesced epilogue, two 32 KB halves --------
  const long long coff = (long long)(z >> czs) * czr + (long long)(z & czm) * czc;
  const long long zr = (long long)z * rstr;
  const int rr = (lane >> 4) * 4;
  unsigned short* flat = &sh[0];
  unsigned short* Cb = (unsigned short*)Cv;
  const long long rbase = (OM == 2) ? (long long)n0 : (long long)m0;
  const long long cbase = (OM == 2) ? (long long)m0 : (long long)n0;

#pragma unroll
  for (int half = 0; half < 2; ++half) {
    const bool mine = (OM == 2) ? ((wn >> 1) == half) : (wm == half);
    if (mine) {
#pragma unroll
      for (int j = 0; j < 4; ++j) {
        const int col = n0 + wn * 64 + j * 16 + fr;
        const float bval = bias ? bias[(long long)(z & biasm) * bstr + col] : 0.f;
        const float ca = cAdd ? cAdd[zr + col] : 0.f;
#pragma unroll
        for (int i = 0; i < 4; ++i) {
#pragma unroll
          for (int r = 0; r < 4; ++r) {
            const int row = m0 + wm * 64 + i * 16 + rr + r;
            const float ra = rAdd ? rAdd[zr + row] : 0.f;
            const float val = (acc[i][j][r] + ra + ca) * scale + bval;
            const int rowL = wm * 64 + i * 16 + rr + r;   // 0..127
            const int colL = wn * 64 + j * 16 + fr;       // 0..255
            if constexpr (OM == 2) {
              const int lR = colL - half * 128;           // 0..127, image [128][128]
              flat[lR * 128 + (rowL ^ ((lR & 7) << 3))] = f2bf(val);
            } else {
              const int lR = rowL - half * 64;            // 0..63, image [64][256]
              flat[lR * 256 + (colL ^ ((lR & 7) << 3))] = f2bf(val);
            }
          }
        }
      }
    }
    __builtin_amdgcn_s_barrier();
    if constexpr (OM == 2) {
#pragma unroll
      for (int it = 0; it < 4; ++it) {
        const int t = it * 512 + tid;
        const int R = t >> 4;        // 0..127
        const int Cq = t & 15;       // 16 quads of 8
        const int q = Cq ^ (R & 7);
        const b16x8 v = *(const b16x8*)&flat[R * 128 + q * 8];
        *(b16x8*)(Cb + coff + (rbase + half * 128 + R) * ldc + cbase + Cq * 8) = v;
      }
    } else {
#pragma unroll
      for (int it = 0; it < 4; ++it) {
        const int t = it * 512 + tid;
        const int R = t >> 5;        // 0..63
        const int Cq = t & 31;       // 32 quads of 8
        const int q = Cq ^ (R & 7);
        const b16x8 v = *(const b16x8*)&flat[R * 256 + q * 8];
        *(b16x8*)(Cb + coff + (rbase + half * 64 + R) * ldc + cbase + Cq * 8) = v;
      }
    }
    __builtin_amdgcn_s_barrier();
  }
}

// ================= 256x256 stage-early GEMM (R6) — out-proj only =========
#define STAGE_A8(nb, koff, i)                                  \
  gload_lds16(gaL + (long long)((i) * 8) * lda + (koff) + scol, \
              &sh[nb][(wid * 32 + (i) * 8) * 64])
#define STAGE_B8(nb, koff, i)                                  \
  gload_lds16(gbL + (long long)((i) * 8) * ldb + (koff) + scol, \
              &sh[2 + (nb)][(wid * 32 + (i) * 8) * 64])

template <int OM>
__global__ __launch_bounds__(512, 2) void k_gemm8p(
    const unsigned short* __restrict__ A, const unsigned short* __restrict__ Bt,
    void* __restrict__ Cv, const float* __restrict__ bias,
    const float* __restrict__ rAdd, const float* __restrict__ cAdd,
    int K, int lda, int ldb, int ldc,
    int azs, int azm, long long azr,
    int bzs, int bzm, long long bzr,
    int czs, long long czr, int czm, int czc,
    int biasm, int bstr, int rstr, float scale, int kzm, int kzr) {
  __shared__ unsigned short sh[4][256 * 64];
  const int tid = threadIdx.x, wid = tid >> 6, lane = tid & 63;
  const int wm = wid >> 2, wn = wid & 3;

  const int gx = gridDim.x, gy = gridDim.y;
  const int nwg = gx * gy * gridDim.z;
  const int bidL = blockIdx.x + gx * (blockIdx.y + gy * blockIdx.z);
  const int q8 = nwg >> 3;
  const int idx = (bidL & 7) * q8 + (bidL >> 3);
  const int bx = idx % gx;
  const int rem = idx / gx;
  const int by = rem % gy;
  const int z = rem / gy;

  const int m0 = by * 256, n0 = bx * 256;
  const int kstart = (z & kzm) * kzr;
  const unsigned short* Az = A + (long long)((z >> azs) & azm) * azr + (long long)m0 * lda + kstart;
  const unsigned short* Bz = Bt + (long long)((z >> bzs) & bzm) * bzr + (long long)n0 * ldb + kstart;

  const int scol = (((lane & 7) ^ ((lane >> 3) & 7)) << 3);
  const unsigned short* gaL = Az + (long long)(wid * 32 + (lane >> 3)) * lda;
  const unsigned short* gbL = Bz + (long long)(wid * 32 + (lane >> 3)) * ldb;

  const int fr = lane & 15, kq = (lane >> 4) * 8;
  const int fsw = (fr & 7) << 3;
  const int rc0 = kq ^ fsw;
  const int rc1 = (32 + kq) ^ fsw;
  const int aBase = (wm * 128 + fr) * 64;
  const int bBase = (wn * 64 + fr) * 64;

  f32x4 acc[8][4] = {};
  b16x8 afr[4][2], bfr[4][2];
  const int NT = K >> 6;

#pragma unroll
  for (int i = 0; i < 4; ++i) { STAGE_A8(0, 0, i); STAGE_B8(0, 0, i); }

  for (int kt = 0; kt < NT; ++kt) {
    const int cur = kt & 1, nb = cur ^ 1;
    if (kt + 1 < NT) {
      const int ko = (kt + 1) << 6;
#pragma unroll
      for (int i = 0; i < 4; ++i) { STAGE_A8(nb, ko, i); STAGE_B8(nb, ko, i); }
      asm volatile("s_waitcnt vmcnt(8)" ::: "memory");
    } else {
      asm volatile("s_waitcnt vmcnt(0)" ::: "memory");
    }
    __builtin_amdgcn_s_barrier();
    __builtin_amdgcn_sched_barrier(0);

#pragma unroll
    for (int i = 0; i < 4; ++i) {
      afr[i][0] = *(const b16x8*)&sh[cur][aBase + i * 1024 + rc0];
      afr[i][1] = *(const b16x8*)&sh[cur][aBase + i * 1024 + rc1];
    }
#pragma unroll
    for (int j = 0; j < 2; ++j) {
      bfr[j][0] = *(const b16x8*)&sh[2 + cur][bBase + j * 1024 + rc0];
      bfr[j][1] = *(const b16x8*)&sh[2 + cur][bBase + j * 1024 + rc1];
    }
    __builtin_amdgcn_s_setprio(1);
#pragma unroll
    for (int t = 0; t < 2; ++t)
#pragma unroll
      for (int i = 0; i < 4; ++i)
#pragma unroll
        for (int j = 0; j < 2; ++j)
          acc[i][j] = __builtin_amdgcn_mfma_f32_16x16x32_bf16(afr[i][t], bfr[j][t], acc[i][j], 0, 0, 0);
    __builtin_amdgcn_s_setprio(0);
#pragma unroll
    for (int j = 2; j < 4; ++j) {
      bfr[j][0] = *(const b16x8*)&sh[2 + cur][bBase + j * 1024 + rc0];
      bfr[j][1] = *(const b16x8*)&sh[2 + cur][bBase + j * 1024 + rc1];
    }
    __builtin_amdgcn_s_setprio(1);
#pragma unroll
    for (int t = 0; t < 2; ++t)
#pragma unroll
      for (int i = 0; i < 4; ++i)
#pragma unroll
        for (int j = 2; j < 4; ++j)
          acc[i][j] = __builtin_amdgcn_mfma_f32_16x16x32_bf16(afr[i][t], bfr[j][t], acc[i][j], 0, 0, 0);
    __builtin_amdgcn_s_setprio(0);
#pragma unroll
    for (int i = 0; i < 4; ++i) {
      afr[i][0] = *(const b16x8*)&sh[cur][aBase + (i + 4) * 1024 + rc0];
      afr[i][1] = *(const b16x8*)&sh[cur][aBase + (i + 4) * 1024 + rc1];
    }
    __builtin_amdgcn_s_setprio(1);
#pragma unroll
    for (int t = 0; t < 2; ++t)
#pragma unroll
      for (int i = 0; i < 4; ++i)
#pragma unroll
        for (int j = 0; j < 2; ++j)
          acc[i + 4][j] = __builtin_amdgcn_mfma_f32_16x16x32_bf16(afr[i][t], bfr[j][t], acc[i + 4][j], 0, 0, 0);
    __builtin_amdgcn_s_setprio(0);
    __builtin_amdgcn_s_setprio(1);
#pragma unroll
    for (int t = 0; t < 2; ++t)
#pragma unroll
      for (int i = 0; i < 4; ++i)
#pragma unroll
        for (int j = 2; j < 4; ++j)
          acc[i + 4][j] = __builtin_amdgcn_mfma_f32_16x16x32_bf16(afr[i][t], bfr[j][t], acc[i + 4][j], 0, 0, 0);
    __builtin_amdgcn_s_setprio(0);

    __builtin_amdgcn_s_barrier();
  }

  const long long coff = (long long)(z >> czs) * czr + (long long)(z & czm) * czc;
  const long long zr = (long long)z * rstr;
  const int rr = (lane >> 4) * 4;
  float* fflat = (float*)&sh[0][0];
  float* Cf = (float*)Cv;
#pragma unroll
  for (int half = 0; half < 2; ++half) {
    if (wm == half) {
#pragma unroll
      for (int j = 0; j < 4; ++j) {
        const int col = n0 + wn * 64 + j * 16 + fr;
        const float bval = bias ? bias[(long long)(z & biasm) * bstr + col] : 0.f;
        const float ca = cAdd ? cAdd[zr + col] : 0.f;
#pragma unroll
        for (int i = 0; i < 8; ++i) {
#pragma unroll
          for (int r = 0; r < 4; ++r) {
            const int row = m0 + wm * 128 + i * 16 + rr + r;
            const float ra = rAdd ? rAdd[zr + row] : 0.f;
            const float val = (acc[i][j][r] + ra + ca) * scale + bval;
            const int Rl = i * 16 + rr + r;
            const int Cl = wn * 64 + j * 16 + fr;
            fflat[Rl * 256 + (Cl ^ ((Rl & 7) << 2))] = val;
          }
        }
      }
    }
    __builtin_amdgcn_s_barrier();
#pragma unroll
    for (int it = 0; it < 16; ++it) {
      const int t = it * 512 + tid;
      const int R = t >> 6;
      const int Cq = t & 63;
      const int q = Cq ^ (R & 7);
      const float4 v = *(const float4*)&fflat[R * 256 + q * 4];
      *(float4*)(Cf + coff + (long long)(m0 + half * 128 + R) * ldc + n0 + Cq * 4) = v;
    }
    __builtin_amdgcn_s_barrier();
  }
}

// ---------------- out = sum of 4 f32 partials + bias(per 512 cols) ----------------
__global__ __launch_bounds__(256) void k_reduce4(const float* __restrict__ p,
                                                 const float* __restrict__ bo,
                                                 float* __restrict__ out) {
  const long long i = (long long)blockIdx.x * 256 + threadIdx.x;
  const float4* p4 = (const float4*)p;
  float4 a = p4[i], b = p4[i + 1048576], c = p4[i + 2097152], d = p4[i + 3145728];
  const float4 bb = ((const float4*)bo)[i & 127];
  float4 o;
  o.x = a.x + b.x + c.x + d.x + bb.x;
  o.y = a.y + b.y + c.y + d.y + bb.y;
  o.z = a.z + b.z + c.z + d.z + bb.z;
  o.w = a.w + b.w + c.w + d.w + bb.w;
  ((float4*)out)[i] = o;
}

extern "C" void kernel_launch(void* const* d_in, const int* in_sizes, int n_in,
                              void* d_out, int out_size, void* d_ws, size_t ws_size,
                              hipStream_t stream) {
  const float* in1 = (const float*)d_in[0];
  const float* in2 = (const float*)d_in[1];
  const float* in3 = (const float*)d_in[2];
  const float* Wq = (const float*)d_in[3];
  const float* bq = (const float*)d_in[4];
  const float* Wk = (const float*)d_in[5];
  const float* bk = (const float*)d_in[6];
  const float* Wv = (const float*)d_in[7];
  const float* bv = (const float*)d_in[8];
  const float* Wo = (const float*)d_in[9];
  const float* bo = (const float*)d_in[10];

  const long long MB = 1024 * 1024;
  typedef unsigned short us;
  unsigned char* w = (unsigned char*)d_ws;
  us* in2b = (us*)(w);                 // 8 MB
  us* Tbuf = (us*)(w + 8 * MB);        // 64 MB (T, then concat per-chunk)
  us* Vt = (us*)(w + 72 * MB);         // 64 MB (then out-proj partials)
  us* wvt = (us*)(w + 136 * MB);       // 4 MB
  us* wot = (us*)(w + 140 * MB);       // 4 MB
  us* scb = (us*)(w + 144 * MB);       // 64 MB (scores/P bf16, in-place)
  us* in1b = (us*)(w + 208 * MB);      // 8 MB
  us* in3b = (us*)(w + 216 * MB);      // 8 MB
  us* wqb = (us*)(w + 224 * MB);       // 4 MB
  us* wkb = (us*)(w + 228 * MB);       // 4 MB
  us* Gt = (us*)(w + 232 * MB);        // 4 MB
  float* rt = (float*)(w + 236 * MB);  // 256 KB
  float* ct = (float*)(w + 236 * MB + (256 << 10));
  float* ubuf = (float*)(w + 237 * MB);
  float* vbuf = (float*)(w + 237 * MB + (16 << 10));
  float* cbuf = (float*)(w + 237 * MB + (32 << 10));
  float* partials = (float*)(w + 72 * MB);  // 64 MB over Vt (dead by then)
  if ((long long)ws_size < 238 * MB) return;

  const float iscale = 0.04419417382415922f;  // 1/sqrt(512)
  const long long SD = 1024 * 512;            // 524288

  // conversions / transposes
  k_conv_bf16<<<4096, 256, 0, stream>>>(in1, in1b, 1048576);
  k_conv_bf16<<<4096, 256, 0, stream>>>(in2, in2b, 1048576);
  k_conv_bf16<<<4096, 256, 0, stream>>>(in3, in3b, 1048576);
  k_conv_bf16<<<2048, 256, 0, stream>>>(Wq, wqb, 524288);
  k_conv_bf16<<<2048, 256, 0, stream>>>(Wk, wkb, 524288);
  k_transpose_bf16<<<dim3(16, 16, 8), dim3(32, 8), 0, stream>>>(Wv, wvt, 512, 512);
  k_transpose_bf16<<<dim3(16, 128, 1), dim3(32, 8), 0, stream>>>(Wo, wot, 4096, 512);

  // bias cross-terms
  k_uv<<<dim3(1024, 2), 256, 0, stream>>>(Wq, bk, Wk, bq, ubuf, vbuf);
  k_bdot<<<1, 512, 0, stream>>>(bq, bk, cbuf);
  k_rtct<<<dim3(8192, 2), 256, 0, stream>>>(in1, in2, ubuf, vbuf, cbuf, rt, ct);

  // Gt[h] = Wk[h] Wq[h]^T  (small; old kernel)
  k_gemm_bt<1><<<dim3(4, 4, 8), 256, 0, stream>>>(
      wkb, wqb, Gt, nullptr, nullptr, nullptr, 512, 512, 512, 512,
      0, 7, 262144LL, 0, 7, 262144LL, 0, 262144LL, 0, 0, 0, 0, 0, 1.f);

  // T[z=b*8+h] = X1[b] G[h]   [64][1024][512] bf16
  k_g32<1><<<dim3(2, 8, 64), 512, 0, stream>>>(
      in1b, Gt, Tbuf, nullptr, nullptr, nullptr, 512, 512, 512, 512,
      3, 7, SD, 0, 7, 262144LL, 0, SD, 0, 0, 0, 0, 0, 1.f);

  // V-proj transposed: Vt[z][e][s]  [64][512][1024] bf16, +bv
  k_g32<2><<<dim3(2, 8, 64), 512, 0, stream>>>(
      in3b, wvt, Vt, bv, nullptr, nullptr, 512, 512, 512, 1024,
      3, 7, SD, 0, 7, 262144LL, 0, SD, 0, 0, 7, 512, 0, 1.f);

  // attention in 2 chunks of 4 batches (32 heads each)
  for (int c = 0; c < 2; ++c) {
    // scores[zz][i][j] = (T X2^T + rt + ct) * iscale -> bf16
    k_g32<1><<<dim3(4, 8, 32), 512, 0, stream>>>(
        Tbuf + (long long)c * 32 * SD, in2b + (long long)c * 4 * SD, scb, nullptr,
        rt + c * 32768, ct + c * 32768, 512, 512, 512, 1024,
        0, 31, SD, 3, 3, SD, 0, 1048576LL, 0, 0, 0, 0, 1024, iscale);
    k_softmax_bf16<<<8192, 256, 0, stream>>>(scb);
    // heads -> concat[(c*4+b')*1024 + i][h*512 + e]
    k_g32<1><<<dim3(2, 8, 32), 512, 0, stream>>>(
        scb, Vt + (long long)c * 32 * SD, Tbuf + (long long)c * 16777216LL, nullptr,
        nullptr, nullptr, 1024, 1024, 1024, 4096,
        0, 31, 1048576LL, 0, 31, SD, 3, 4194304LL, 7, 512, 0, 0, 0, 1.f);
  }

  // out-proj split-K=4: partials[ks] = concat[:, ks*1024:+1024] @ wot[:, same]^T
  k_gemm8p<0><<<dim3(2, 32, 4), 512, 0, stream>>>(
      Tbuf, wot, partials, nullptr, nullptr, nullptr, 1024, 4096, 4096, 512,
      0, 0, 0, 0, 0, 0, 0, 4194304LL, 0, 0, 0, 0, 0, 1.f, 3, 1024);
  k_reduce4<<<4096, 256, 0, stream>>>(partials, bo, (float*)d_out);
}

// Round 11
// 465.013 us; speedup vs baseline: 1.1111x; 1.0947x over previous
//
#include <hip/hip_runtime.h>
#include <hip/hip_bf16.h>

#define DEV static __device__ __forceinline__

typedef float f32x4 __attribute__((ext_vector_type(4)));
typedef __bf16 b16x8 __attribute__((ext_vector_type(8)));

DEV unsigned short f2bf(float f) {
  union { __hip_bfloat16 h; unsigned short u; } cv;
  cv.h = __float2bfloat16(f);
  return cv.u;
}

DEV void gload_lds16(const unsigned short* g, unsigned short* l) {
  __builtin_amdgcn_global_load_lds(
      (__attribute__((address_space(1))) void*)g,
      (__attribute__((address_space(3))) void*)l, 16, 0, 0);
}

// ---------------- all f32->bf16 conversions in ONE launch ----------------
__global__ __launch_bounds__(256) void k_convall(
    const float* __restrict__ in1, const float* __restrict__ in2,
    const float* __restrict__ in3, const float* __restrict__ Wq,
    const float* __restrict__ Wk,
    unsigned short* __restrict__ in1b, unsigned short* __restrict__ in2b,
    unsigned short* __restrict__ in3b, unsigned short* __restrict__ wqb,
    unsigned short* __restrict__ wkb) {
  const int b = blockIdx.x;
  const float* src;
  unsigned short* dst;
  long long off;
  if (b < 4096) { src = in1; dst = in1b; off = b; }
  else if (b < 8192) { src = in2; dst = in2b; off = b - 4096; }
  else if (b < 12288) { src = in3; dst = in3b; off = b - 8192; }
  else if (b < 14336) { src = Wq; dst = wqb; off = b - 12288; }
  else { src = Wk; dst = wkb; off = b - 14336; }
  const long long i = off * 256 + threadIdx.x;
  const float4 v = ((const float4*)src)[i];
  ushort4 o;
  o.x = f2bf(v.x); o.y = f2bf(v.y); o.z = f2bf(v.z); o.w = f2bf(v.w);
  ((ushort4*)dst)[i] = o;
}

// ---------------- Wv (8x512x512) and Wo (4096x512) transposes, ONE launch ----
__global__ __launch_bounds__(256) void k_transall(const float* __restrict__ Wv,
                                                  const float* __restrict__ Wo,
                                                  unsigned short* __restrict__ wvt,
                                                  unsigned short* __restrict__ wot) {
  __shared__ float t[32][33];
  const int yy = blockIdx.y;
  const float* src;
  unsigned short* dst;
  long long zo;
  int R, C, r0;
  const int c0 = blockIdx.x * 32;
  if (yy < 128) {  // Wv slice z = yy>>4
    src = Wv; dst = wvt; R = 512; C = 512;
    zo = (long long)(yy >> 4) * 512 * 512;
    r0 = (yy & 15) * 32;
  } else {  // Wo
    src = Wo; dst = wot; R = 4096; C = 512;
    zo = 0;
    r0 = (yy - 128) * 32;
  }
  const int tx = threadIdx.x & 31, ty = threadIdx.x >> 5;
#pragma unroll
  for (int i = 0; i < 4; ++i)
    t[ty + i * 8][tx] = src[zo + (long long)(r0 + ty + i * 8) * C + c0 + tx];
  __syncthreads();
#pragma unroll
  for (int i = 0; i < 4; ++i)
    dst[zo + (long long)(c0 + ty + i * 8) * R + r0 + tx] = f2bf(t[tx][ty + i * 8]);
}

// ---------------- u[h,d]=sum_e Wq[h,d,e]*bk[h,e] (sel0) / v from Wk,bq (sel1) ----------------
__global__ __launch_bounds__(256) void k_uv(const float* __restrict__ Wq, const float* __restrict__ bk,
                                            const float* __restrict__ Wk, const float* __restrict__ bq,
                                            float* __restrict__ u, float* __restrict__ v) {
  const int sel = blockIdx.y;
  const float* W = sel ? Wk : Wq;
  const float* bb = sel ? bq : bk;
  float* dst = sel ? v : u;
  const int wave = threadIdx.x >> 6, lane = threadIdx.x & 63;
  const int idx = blockIdx.x * 4 + wave;
  const int h = idx >> 9, d = idx & 511;
  const float* wr = W + ((long long)h * 512 + d) * 512 + lane * 8;
  const float* br = bb + h * 512 + lane * 8;
  float s = 0.f;
#pragma unroll
  for (int k = 0; k < 8; ++k) s += wr[k] * br[k];
#pragma unroll
  for (int off = 32; off; off >>= 1) s += __shfl_xor(s, off);
  if (lane == 0) dst[h * 512 + d] = s;
}

// ---------------- c[h] = bq[h].bk[h] ----------------
__global__ __launch_bounds__(512) void k_bdot(const float* __restrict__ bq,
                                              const float* __restrict__ bk,
                                              float* __restrict__ c) {
  const int wave = threadIdx.x >> 6, lane = threadIdx.x & 63;
  const float* a = bq + wave * 512 + lane * 8;
  const float* b = bk + wave * 512 + lane * 8;
  float s = 0.f;
#pragma unroll
  for (int k = 0; k < 8; ++k) s += a[k] * b[k];
#pragma unroll
  for (int off = 32; off; off >>= 1) s += __shfl_xor(s, off);
  if (lane == 0) c[wave] = s;
}

// ---------------- rt[b*8+h][i] = in1[b,i,:].u[h,:] + c[h]; ct from in2,v ----------------
__global__ __launch_bounds__(256) void k_rtct(const float* __restrict__ in1, const float* __restrict__ in2,
                                              const float* __restrict__ u, const float* __restrict__ v,
                                              const float* __restrict__ cbuf,
                                              float* __restrict__ rt, float* __restrict__ ct) {
  const int sel = blockIdx.y;
  const float* src = sel ? in2 : in1;
  const float* vec = sel ? v : u;
  float* dst = sel ? ct : rt;
  const int row = blockIdx.x;
  __shared__ float x[512];
  const float* p = src + (long long)row * 512;
  x[threadIdx.x] = p[threadIdx.x];
  x[threadIdx.x + 256] = p[threadIdx.x + 256];
  __syncthreads();
  const int wave = threadIdx.x >> 6, lane = threadIdx.x & 63;
  const int b = row >> 10, i = row & 1023;
#pragma unroll
  for (int t = 0; t < 2; ++t) {
    const int h = wave * 2 + t;
    const float* wv = vec + h * 512;
    float s = 0.f;
#pragma unroll
    for (int k = 0; k < 8; ++k) s += x[lane + k * 64] * wv[lane + k * 64];
#pragma unroll
    for (int off = 32; off; off >>= 1) s += __shfl_xor(s, off);
    if (lane == 0)
      dst[((long long)(b * 8 + h)) * 1024 + i] = s + (sel ? 0.f : cbuf[h]);
  }
}

// ---------------- in-place row softmax over 1024 bf16, one wave per row ----------------
__global__ __launch_bounds__(256) void k_softmax_bf16(unsigned short* __restrict__ P) {
  const int wave = threadIdx.x >> 6, lane = threadIdx.x & 63;
  unsigned short* p = P + ((long long)blockIdx.x * 4 + wave) * 1024 + lane * 16;
  const b16x8 v0 = *(const b16x8*)p;
  const b16x8 v1 = *(const b16x8*)(p + 8);
  float f[16];
#pragma unroll
  for (int j = 0; j < 8; ++j) { f[j] = (float)v0[j]; f[8 + j] = (float)v1[j]; }
  float mx = f[0];
#pragma unroll
  for (int j = 1; j < 16; ++j) mx = fmaxf(mx, f[j]);
#pragma unroll
  for (int off = 32; off; off >>= 1) mx = fmaxf(mx, __shfl_xor(mx, off));
  float sum = 0.f;
#pragma unroll
  for (int j = 0; j < 16; ++j) { f[j] = __expf(f[j] - mx); sum += f[j]; }
#pragma unroll
  for (int off = 32; off; off >>= 1) sum += __shfl_xor(sum, off);
  const float inv = 1.f / sum;
  b16x8 o0, o1;
#pragma unroll
  for (int j = 0; j < 8; ++j) { o0[j] = (__bf16)(f[j] * inv); o1[j] = (__bf16)(f[8 + j] * inv); }
  *(b16x8*)p = o0;
  *(b16x8*)(p + 8) = o1;
}

// ---------------- old 128x128 GEMM (small Gt GEMM) ----------------
template <int OM>
__global__ __launch_bounds__(256) void k_gemm_bt(
    const unsigned short* __restrict__ A, const unsigned short* __restrict__ Bt,
    void* __restrict__ Cv, const float* __restrict__ bias,
    const float* __restrict__ rAdd, const float* __restrict__ cAdd,
    int K, int lda, int ldb, int ldc,
    int azs, int azm, long long azr,
    int bzs, int bzm, long long bzr,
    int czs, long long czr, int czm, int czc,
    int biasm, int bstr, int rstr, float scale) {
  __shared__ unsigned short lA[128 * 64];
  __shared__ unsigned short lB[128 * 64];
  const int tid = threadIdx.x, wave = tid >> 6, lane = tid & 63;
  const int z = blockIdx.z;
  const int m0 = blockIdx.y * 128, n0 = blockIdx.x * 128;
  const unsigned short* Az = A + (long long)((z >> azs) & azm) * azr + (long long)m0 * lda;
  const unsigned short* Bz = Bt + (long long)((z >> bzs) & bzm) * bzr + (long long)n0 * ldb;

  const int srow = wave * 32 + (lane >> 3);
  const int scol = (lane & 7) * 8;
  const unsigned short* ga = Az + (long long)srow * lda + scol;
  const unsigned short* gb = Bz + (long long)srow * ldb + scol;
  unsigned short* laBase = &lA[(wave * 32) * 64];
  unsigned short* lbBase = &lB[(wave * 32) * 64];

  f32x4 acc[4][4] = {};
  const int wr = (wave >> 1) * 64, wc = (wave & 1) * 64;
  const int fr = lane & 15, kq = (lane >> 4) * 8;

  for (int k0 = 0; k0 < K; k0 += 64) {
#pragma unroll
    for (int i = 0; i < 4; ++i) {
      gload_lds16(ga + (long long)(i * 8) * lda + k0, laBase + (i * 8) * 64);
      gload_lds16(gb + (long long)(i * 8) * ldb + k0, lbBase + (i * 8) * 64);
    }
    __syncthreads();
#pragma unroll
    for (int kk = 0; kk < 64; kk += 32) {
      b16x8 af[4], bf[4];
#pragma unroll
      for (int i = 0; i < 4; ++i)
        af[i] = *(const b16x8*)&lA[(wr + i * 16 + fr) * 64 + kk + kq];
#pragma unroll
      for (int j = 0; j < 4; ++j)
        bf[j] = *(const b16x8*)&lB[(wc + j * 16 + fr) * 64 + kk + kq];
#pragma unroll
      for (int i = 0; i < 4; ++i)
#pragma unroll
        for (int j = 0; j < 4; ++j)
          acc[i][j] = __builtin_amdgcn_mfma_f32_16x16x32_bf16(af[i], bf[j], acc[i][j], 0, 0, 0);
    }
    __syncthreads();
  }

  const long long coff = (long long)(z >> czs) * czr + (long long)(z & czm) * czc;
  const long long zr = (long long)z * rstr;
  const int rr = (lane >> 4) * 4;
#pragma unroll
  for (int j = 0; j < 4; ++j) {
    const int col = n0 + wc + j * 16 + fr;
    const float bval = bias ? bias[(long long)(z & biasm) * bstr + col] : 0.f;
    const float ca = cAdd ? cAdd[zr + col] : 0.f;
#pragma unroll
    for (int i = 0; i < 4; ++i) {
#pragma unroll
      for (int r = 0; r < 4; ++r) {
        const int row = m0 + wr + i * 16 + rr + r;
        const float ra = rAdd ? rAdd[zr + row] : 0.f;
        const float val = (acc[i][j][r] + ra + ca) * scale + bval;
        if constexpr (OM == 1) {
          ((unsigned short*)Cv)[coff + (long long)row * ldc + col] = f2bf(val);
        } else if constexpr (OM == 2) {
          ((unsigned short*)Cv)[coff + (long long)col * ldc + row] = f2bf(val);
        } else {
          ((float*)Cv)[coff + (long long)row * ldc + col] = val;
        }
      }
    }
  }
}

// ================= 256x256 stage-early GEMM, LDS-coalesced epilogue (R6) ====
#define STAGE_A8(nb, koff, i)                                  \
  gload_lds16(gaL + (long long)((i) * 8) * lda + (koff) + scol, \
              &sh[nb][(wid * 32 + (i) * 8) * 64])
#define STAGE_B8(nb, koff, i)                                  \
  gload_lds16(gbL + (long long)((i) * 8) * ldb + (koff) + scol, \
              &sh[2 + (nb)][(wid * 32 + (i) * 8) * 64])

template <int OM>
__global__ __launch_bounds__(512, 2) void k_gemm8p(
    const unsigned short* __restrict__ A, const unsigned short* __restrict__ Bt,
    void* __restrict__ Cv, const float* __restrict__ bias,
    const float* __restrict__ rAdd, const float* __restrict__ cAdd,
    int K, int lda, int ldb, int ldc,
    int azs, int azm, long long azr,
    int bzs, int bzm, long long bzr,
    int czs, long long czr, int czm, int czc,
    int biasm, int bstr, int rstr, float scale, int kzm, int kzr) {
  __shared__ unsigned short sh[4][256 * 64];  // [0..1]=A dbuf, [2..3]=B dbuf
  const int tid = threadIdx.x, wid = tid >> 6, lane = tid & 63;
  const int wm = wid >> 2, wn = wid & 3;

  // XCD-chunked bijective block swizzle (nwg multiple of 8 for all uses)
  const int gx = gridDim.x, gy = gridDim.y;
  const int nwg = gx * gy * gridDim.z;
  const int bidL = blockIdx.x + gx * (blockIdx.y + gy * blockIdx.z);
  const int q8 = nwg >> 3;
  const int idx = (bidL & 7) * q8 + (bidL >> 3);
  const int bx = idx % gx;
  const int rem = idx / gx;
  const int by = rem % gy;
  const int z = rem / gy;

  const int m0 = by * 256, n0 = bx * 256;
  const int kstart = (z & kzm) * kzr;
  const unsigned short* Az = A + (long long)((z >> azs) & azm) * azr + (long long)m0 * lda + kstart;
  const unsigned short* Bz = Bt + (long long)((z >> bzs) & bzm) * bzr + (long long)n0 * ldb + kstart;

  const int scol = (((lane & 7) ^ ((lane >> 3) & 7)) << 3);
  const unsigned short* gaL = Az + (long long)(wid * 32 + (lane >> 3)) * lda;
  const unsigned short* gbL = Bz + (long long)(wid * 32 + (lane >> 3)) * ldb;

  const int fr = lane & 15, kq = (lane >> 4) * 8;
  const int fsw = (fr & 7) << 3;
  const int rc0 = kq ^ fsw;
  const int rc1 = (32 + kq) ^ fsw;
  const int aBase = (wm * 128 + fr) * 64;
  const int bBase = (wn * 64 + fr) * 64;

  f32x4 acc[8][4] = {};
  b16x8 afr[4][2], bfr[4][2];
  const int NT = K >> 6;

#pragma unroll
  for (int i = 0; i < 4; ++i) { STAGE_A8(0, 0, i); STAGE_B8(0, 0, i); }

  for (int kt = 0; kt < NT; ++kt) {
    const int cur = kt & 1, nb = cur ^ 1;
    if (kt + 1 < NT) {
      const int ko = (kt + 1) << 6;
#pragma unroll
      for (int i = 0; i < 4; ++i) { STAGE_A8(nb, ko, i); STAGE_B8(nb, ko, i); }
      asm volatile("s_waitcnt vmcnt(8)" ::: "memory");
    } else {
      asm volatile("s_waitcnt vmcnt(0)" ::: "memory");
    }
    __builtin_amdgcn_s_barrier();
    __builtin_amdgcn_sched_barrier(0);

    // Q0
#pragma unroll
    for (int i = 0; i < 4; ++i) {
      afr[i][0] = *(const b16x8*)&sh[cur][aBase + i * 1024 + rc0];
      afr[i][1] = *(const b16x8*)&sh[cur][aBase + i * 1024 + rc1];
    }
#pragma unroll
    for (int j = 0; j < 2; ++j) {
      bfr[j][0] = *(const b16x8*)&sh[2 + cur][bBase + j * 1024 + rc0];
      bfr[j][1] = *(const b16x8*)&sh[2 + cur][bBase + j * 1024 + rc1];
    }
    __builtin_amdgcn_s_setprio(1);
#pragma unroll
    for (int t = 0; t < 2; ++t)
#pragma unroll
      for (int i = 0; i < 4; ++i)
#pragma unroll
        for (int j = 0; j < 2; ++j)
          acc[i][j] = __builtin_amdgcn_mfma_f32_16x16x32_bf16(afr[i][t], bfr[j][t], acc[i][j], 0, 0, 0);
    __builtin_amdgcn_s_setprio(0);
    // Q1
#pragma unroll
    for (int j = 2; j < 4; ++j) {
      bfr[j][0] = *(const b16x8*)&sh[2 + cur][bBase + j * 1024 + rc0];
      bfr[j][1] = *(const b16x8*)&sh[2 + cur][bBase + j * 1024 + rc1];
    }
    __builtin_amdgcn_s_setprio(1);
#pragma unroll
    for (int t = 0; t < 2; ++t)
#pragma unroll
      for (int i = 0; i < 4; ++i)
#pragma unroll
        for (int j = 2; j < 4; ++j)
          acc[i][j] = __builtin_amdgcn_mfma_f32_16x16x32_bf16(afr[i][t], bfr[j][t], acc[i][j], 0, 0, 0);
    __builtin_amdgcn_s_setprio(0);
    // Q2
#pragma unroll
    for (int i = 0; i < 4; ++i) {
      afr[i][0] = *(const b16x8*)&sh[cur][aBase + (i + 4) * 1024 + rc0];
      afr[i][1] = *(const b16x8*)&sh[cur][aBase + (i + 4) * 1024 + rc1];
    }
    __builtin_amdgcn_s_setprio(1);
#pragma unroll
    for (int t = 0; t < 2; ++t)
#pragma unroll
      for (int i = 0; i < 4; ++i)
#pragma unroll
        for (int j = 0; j < 2; ++j)
          acc[i + 4][j] = __builtin_amdgcn_mfma_f32_16x16x32_bf16(afr[i][t], bfr[j][t], acc[i + 4][j], 0, 0, 0);
    __builtin_amdgcn_s_setprio(0);
    // Q3
    __builtin_amdgcn_s_setprio(1);
#pragma unroll
    for (int t = 0; t < 2; ++t)
#pragma unroll
      for (int i = 0; i < 4; ++i)
#pragma unroll
        for (int j = 2; j < 4; ++j)
          acc[i + 4][j] = __builtin_amdgcn_mfma_f32_16x16x32_bf16(afr[i][t], bfr[j][t], acc[i + 4][j], 0, 0, 0);
    __builtin_amdgcn_s_setprio(0);

    __builtin_amdgcn_s_barrier();
  }

  // ---------------- LDS-coalesced epilogue ----------------
  const long long coff = (long long)(z >> czs) * czr + (long long)(z & czm) * czc;
  const long long zr = (long long)z * rstr;
  const int rr = (lane >> 4) * 4;
  unsigned short* flat = &sh[0][0];

#pragma unroll
  for (int j = 0; j < 4; ++j) {
    const int col = n0 + wn * 64 + j * 16 + fr;
    const float bval = bias ? bias[(long long)(z & biasm) * bstr + col] : 0.f;
    const float ca = cAdd ? cAdd[zr + col] : 0.f;
#pragma unroll
    for (int i = 0; i < 8; ++i) {
#pragma unroll
      for (int r = 0; r < 4; ++r) {
        const int row = m0 + wm * 128 + i * 16 + rr + r;
        const float ra = rAdd ? rAdd[zr + row] : 0.f;
        const float val = (acc[i][j][r] + ra + ca) * scale + bval;
        const int rowL = wm * 128 + i * 16 + rr + r;
        const int colL = wn * 64 + j * 16 + fr;
        const int sR = (OM == 2) ? colL : rowL;
        const int sC = (OM == 2) ? rowL : colL;
        flat[sR * 256 + (sC ^ ((sR & 7) << 3))] = f2bf(val);
      }
    }
  }
  __builtin_amdgcn_s_barrier();
  const long long rbase = (OM == 2) ? (long long)n0 : (long long)m0;
  const long long cbase = (OM == 2) ? (long long)m0 : (long long)n0;
  unsigned short* Cb = (unsigned short*)Cv;
#pragma unroll
  for (int it = 0; it < 16; ++it) {
    const int t = it * 512 + tid;
    const int R = t >> 5;
    const int Cq = t & 31;
    const int q = Cq ^ (R & 7);
    const b16x8 v = *(const b16x8*)&flat[R * 256 + q * 8];
    *(b16x8*)(Cb + coff + (rbase + R) * ldc + cbase + Cq * 8) = v;
  }
}

// ================= 128x128 stage-early GEMM (R7 k_g128) — out-proj K=4096 =====
#define STAGE_GA(nb, koff, i)                                  \
  gload_lds16(gaL + (long long)((i) * 8) * lda + (koff) + scol, \
              &sh[nb][(wid * 32 + (i) * 8) * 64])
#define STAGE_GB(nb, koff, i)                                  \
  gload_lds16(gbL + (long long)((i) * 8) * ldb + (koff) + scol, \
              &sh[2 + (nb)][(wid * 32 + (i) * 8) * 64])

template <int OM>
__global__ __launch_bounds__(256, 2) void k_g128(
    const unsigned short* __restrict__ A, const unsigned short* __restrict__ Bt,
    void* __restrict__ Cv, const float* __restrict__ bias,
    const float* __restrict__ rAdd, const float* __restrict__ cAdd,
    int K, int lda, int ldb, int ldc,
    int azs, int azm, long long azr,
    int bzs, int bzm, long long bzr,
    int czs, long long czr, int czm, int czc,
    int biasm, int bstr, int rstr, float scale, int kzm, int kzr) {
  __shared__ unsigned short sh[4][128 * 64];  // [0..1]=A dbuf, [2..3]=B dbuf
  const int tid = threadIdx.x, wid = tid >> 6, lane = tid & 63;
  const int wm = wid >> 1, wn = wid & 1;

  const int gx = gridDim.x, gy = gridDim.y;
  const int nwg = gx * gy * gridDim.z;
  const int bidL = blockIdx.x + gx * (blockIdx.y + gy * blockIdx.z);
  const int q8 = nwg >> 3;
  const int idx = (bidL & 7) * q8 + (bidL >> 3);
  const int bx = idx % gx;
  const int rem = idx / gx;
  const int by = rem % gy;
  const int z = rem / gy;

  const int m0 = by * 128, n0 = bx * 128;
  const int kstart = (z & kzm) * kzr;
  const unsigned short* Az = A + (long long)((z >> azs) & azm) * azr + (long long)m0 * lda + kstart;
  const unsigned short* Bz = Bt + (long long)((z >> bzs) & bzm) * bzr + (long long)n0 * ldb + kstart;

  const int scol = (((lane & 7) ^ ((lane >> 3) & 7)) << 3);
  const unsigned short* gaL = Az + (long long)(wid * 32 + (lane >> 3)) * lda;
  const unsigned short* gbL = Bz + (long long)(wid * 32 + (lane >> 3)) * ldb;

  const int fr = lane & 15, kq = (lane >> 4) * 8;
  const int fsw = (fr & 7) << 3;
  const int rc0 = kq ^ fsw;
  const int rc1 = (32 + kq) ^ fsw;
  const int aBase = (wm * 64 + fr) * 64;
  const int bBase = (wn * 64 + fr) * 64;

  f32x4 acc[4][4] = {};
  b16x8 afr[4][2], bfr[4][2];
  const int NT = K >> 6;

#pragma unroll
  for (int i = 0; i < 4; ++i) { STAGE_GA(0, 0, i); STAGE_GB(0, 0, i); }

  for (int kt = 0; kt < NT; ++kt) {
    const int cur = kt & 1, nb = cur ^ 1;
    if (kt + 1 < NT) {
      const int ko = (kt + 1) << 6;
#pragma unroll
      for (int i = 0; i < 4; ++i) { STAGE_GA(nb, ko, i); STAGE_GB(nb, ko, i); }
      asm volatile("s_waitcnt vmcnt(8)" ::: "memory");
    } else {
      asm volatile("s_waitcnt vmcnt(0)" ::: "memory");
    }
    __builtin_amdgcn_s_barrier();
    __builtin_amdgcn_sched_barrier(0);

#pragma unroll
    for (int i = 0; i < 4; ++i) {
      afr[i][0] = *(const b16x8*)&sh[cur][aBase + i * 1024 + rc0];
      afr[i][1] = *(const b16x8*)&sh[cur][aBase + i * 1024 + rc1];
    }
#pragma unroll
    for (int j = 0; j < 4; ++j) {
      bfr[j][0] = *(const b16x8*)&sh[2 + cur][bBase + j * 1024 + rc0];
      bfr[j][1] = *(const b16x8*)&sh[2 + cur][bBase + j * 1024 + rc1];
    }
#pragma unroll
    for (int t = 0; t < 2; ++t)
#pragma unroll
      for (int i = 0; i < 4; ++i)
#pragma unroll
        for (int j = 0; j < 4; ++j)
          acc[i][j] = __builtin_amdgcn_mfma_f32_16x16x32_bf16(afr[i][t], bfr[j][t], acc[i][j], 0, 0, 0);

    __builtin_amdgcn_s_barrier();
  }

  // ---------------- LDS-coalesced epilogue ----------------
  const long long coff = (long long)(z >> czs) * czr + (long long)(z & czm) * czc;
  const long long zr = (long long)z * rstr;
  const int rr = (lane >> 4) * 4;
  unsigned short* flat = &sh[0][0];

  if constexpr (OM == 1 || OM == 2) {
#pragma unroll
    for (int j = 0; j < 4; ++j) {
      const int col = n0 + wn * 64 + j * 16 + fr;
      const float bval = bias ? bias[(long long)(z & biasm) * bstr + col] : 0.f;
      const float ca = cAdd ? cAdd[zr + col] : 0.f;
#pragma unroll
      for (int i = 0; i < 4; ++i) {
#pragma unroll
        for (int r = 0; r < 4; ++r) {
          const int row = m0 + wm * 64 + i * 16 + rr + r;
          const float ra = rAdd ? rAdd[zr + row] : 0.f;
          const float val = (acc[i][j][r] + ra + ca) * scale + bval;
          const int rowL = wm * 64 + i * 16 + rr + r;
          const int colL = wn * 64 + j * 16 + fr;
          const int sR = (OM == 2) ? colL : rowL;
          const int sC = (OM == 2) ? rowL : colL;
          flat[sR * 128 + (sC ^ ((sR & 7) << 3))] = f2bf(val);
        }
      }
    }
    __builtin_amdgcn_s_barrier();
    const long long rbase = (OM == 2) ? (long long)n0 : (long long)m0;
    const long long cbase = (OM == 2) ? (long long)m0 : (long long)n0;
    unsigned short* Cb = (unsigned short*)Cv;
#pragma unroll
    for (int it = 0; it < 8; ++it) {
      const int t = it * 256 + tid;
      const int R = t >> 4;
      const int Cq = t & 15;
      const int q = Cq ^ (R & 7);
      const b16x8 v = *(const b16x8*)&flat[R * 128 + q * 8];
      *(b16x8*)(Cb + coff + (rbase + R) * ldc + cbase + Cq * 8) = v;
    }
  } else {
    // f32: 128x128x4 = 64 KB = full LDS, one pass
    float* fflat = (float*)flat;
    float* Cf = (float*)Cv;
#pragma unroll
    for (int j = 0; j < 4; ++j) {
      const int col = n0 + wn * 64 + j * 16 + fr;
      const float bval = bias ? bias[(long long)(z & biasm) * bstr + col] : 0.f;
      const float ca = cAdd ? cAdd[zr + col] : 0.f;
#pragma unroll
      for (int i = 0; i < 4; ++i) {
#pragma unroll
        for (int r = 0; r < 4; ++r) {
          const int row = m0 + wm * 64 + i * 16 + rr + r;
          const float ra = rAdd ? rAdd[zr + row] : 0.f;
          const float val = (acc[i][j][r] + ra + ca) * scale + bval;
          const int Rl = wm * 64 + i * 16 + rr + r;
          const int Cl = wn * 64 + j * 16 + fr;
          fflat[Rl * 128 + (Cl ^ ((Rl & 7) << 2))] = val;
        }
      }
    }
    __builtin_amdgcn_s_barrier();
#pragma unroll
    for (int it = 0; it < 16; ++it) {
      const int t = it * 256 + tid;
      const int R = t >> 5;
      const int Cq = t & 31;
      const int q = Cq ^ (R & 7);
      const float4 v = *(const float4*)&fflat[R * 128 + q * 4];
      *(float4*)(Cf + coff + (long long)(m0 + R) * ldc + n0 + Cq * 4) = v;
    }
  }
}

extern "C" void kernel_launch(void* const* d_in, const int* in_sizes, int n_in,
                              void* d_out, int out_size, void* d_ws, size_t ws_size,
                              hipStream_t stream) {
  const float* in1 = (const float*)d_in[0];
  const float* in2 = (const float*)d_in[1];
  const float* in3 = (const float*)d_in[2];
  const float* Wq = (const float*)d_in[3];
  const float* bq = (const float*)d_in[4];
  const float* Wk = (const float*)d_in[5];
  const float* bk = (const float*)d_in[6];
  const float* Wv = (const float*)d_in[7];
  const float* bv = (const float*)d_in[8];
  const float* Wo = (const float*)d_in[9];
  const float* bo = (const float*)d_in[10];

  const long long MB = 1024 * 1024;
  typedef unsigned short us;
  unsigned char* w = (unsigned char*)d_ws;
  us* in2b = (us*)(w);                 // 8 MB
  us* Tbuf = (us*)(w + 8 * MB);        // 64 MB (T, then concat per-chunk)
  us* Vt = (us*)(w + 72 * MB);         // 64 MB
  us* wvt = (us*)(w + 136 * MB);       // 4 MB
  us* wot = (us*)(w + 140 * MB);       // 4 MB
  us* scb = (us*)(w + 144 * MB);       // 64 MB (scores/P bf16, in-place)
  us* in1b = (us*)(w + 208 * MB);      // 8 MB
  us* in3b = (us*)(w + 216 * MB);      // 8 MB
  us* wqb = (us*)(w + 224 * MB);       // 4 MB
  us* wkb = (us*)(w + 228 * MB);       // 4 MB
  us* Gt = (us*)(w + 232 * MB);        // 4 MB
  float* rt = (float*)(w + 236 * MB);  // 256 KB
  float* ct = (float*)(w + 236 * MB + (256 << 10));
  float* ubuf = (float*)(w + 237 * MB);
  float* vbuf = (float*)(w + 237 * MB + (16 << 10));
  float* cbuf = (float*)(w + 237 * MB + (32 << 10));
  if ((long long)ws_size < 238 * MB) return;

  const float iscale = 0.04419417382415922f;  // 1/sqrt(512)
  const long long SD = 1024 * 512;            // 524288

  // all conversions (1 launch) + both weight transposes (1 launch)
  k_convall<<<16384, 256, 0, stream>>>(in1, in2, in3, Wq, Wk,
                                       in1b, in2b, in3b, wqb, wkb);
  k_transall<<<dim3(16, 256), 256, 0, stream>>>(Wv, Wo, wvt, wot);

  // bias cross-terms
  k_uv<<<dim3(1024, 2), 256, 0, stream>>>(Wq, bk, Wk, bq, ubuf, vbuf);
  k_bdot<<<1, 512, 0, stream>>>(bq, bk, cbuf);
  k_rtct<<<dim3(8192, 2), 256, 0, stream>>>(in1, in2, ubuf, vbuf, cbuf, rt, ct);

  // Gt[h] = Wk[h] Wq[h]^T
  k_gemm_bt<1><<<dim3(4, 4, 8), 256, 0, stream>>>(
      wkb, wqb, Gt, nullptr, nullptr, nullptr, 512, 512, 512, 512,
      0, 7, 262144LL, 0, 7, 262144LL, 0, 262144LL, 0, 0, 0, 0, 0, 1.f);

  // T[z=b*8+h] = X1[b] G[h]   [64][1024][512] bf16
  k_gemm8p<1><<<dim3(2, 4, 64), 512, 0, stream>>>(
      in1b, Gt, Tbuf, nullptr, nullptr, nullptr, 512, 512, 512, 512,
      3, 7, SD, 0, 7, 262144LL, 0, SD, 0, 0, 0, 0, 0, 1.f, 0, 0);

  // V-proj transposed: Vt[z][e][s]  [64][512][1024] bf16, +bv
  k_gemm8p<2><<<dim3(2, 4, 64), 512, 0, stream>>>(
      in3b, wvt, Vt, bv, nullptr, nullptr, 512, 512, 512, 1024,
      3, 7, SD, 0, 7, 262144LL, 0, SD, 0, 0, 7, 512, 0, 1.f, 0, 0);

  // attention in 2 chunks of 4 batches (32 heads each)
  for (int c = 0; c < 2; ++c) {
    // scores[zz][i][j] = (T X2^T + rt + ct) * iscale -> bf16
    k_gemm8p<1><<<dim3(4, 4, 32), 512, 0, stream>>>(
        Tbuf + (long long)c * 32 * SD, in2b + (long long)c * 4 * SD, scb, nullptr,
        rt + c * 32768, ct + c * 32768, 512, 512, 512, 1024,
        0, 31, SD, 3, 3, SD, 0, 1048576LL, 0, 0, 0, 0, 1024, iscale, 0, 0);
    k_softmax_bf16<<<8192, 256, 0, stream>>>(scb);
    // heads -> concat[(c*4+b')*1024 + i][h*512 + e]
    k_gemm8p<1><<<dim3(2, 4, 32), 512, 0, stream>>>(
        scb, Vt + (long long)c * 32 * SD, Tbuf + (long long)c * 16777216LL, nullptr,
        nullptr, nullptr, 1024, 1024, 1024, 4096,
        0, 31, 1048576LL, 0, 31, SD, 3, 4194304LL, 7, 512, 0, 0, 0, 1.f, 0, 0);
  }

  // out = concat[8192,4096] @ wot^T + bo : single GEMM, K=4096 (64 K-tiles)
  k_g128<0><<<dim3(4, 64, 1), 256, 0, stream>>>(
      Tbuf, wot, d_out, bo, nullptr, nullptr, 4096, 4096, 4096, 512,
      0, 0, 0, 0, 0, 0, 0, 0, 0, 0, 0, 0, 0, 1.f, 0, 0);
}